// Round 1
// baseline (461.434 us; speedup 1.0000x reference)
//
#include <hip/hip_runtime.h>
#include <hip/hip_bf16.h>
#include <math.h>

// Problem constants (from reference)
constexpr int NTOK = 524288;   // T
constexpr int NB   = 4096;     // B (segments / batch)
constexpr int H    = 512;
constexpr float EPS = 1e-5f;

// ---------------------------------------------------------------------------
// K1: fused gather + segment mean.  seg_ids sorted -> one block per segment.
// 128 threads, each owns one float4 column chunk (128*4 = 512 = H).
// ---------------------------------------------------------------------------
__global__ __launch_bounds__(128) void k_gather_mean(
    const int* __restrict__ tokens, const int* __restrict__ seg,
    const float* __restrict__ emb, float* __restrict__ bow) {
  const int b = blockIdx.x;
  // lower_bound(seg, b) and lower_bound(seg, b+1) — wave-uniform binary search
  int lo = 0, hi = NTOK;
  while (lo < hi) { int mid = (lo + hi) >> 1; if (seg[mid] < b) lo = mid + 1; else hi = mid; }
  const int start = lo;
  hi = NTOK;
  while (lo < hi) { int mid = (lo + hi) >> 1; if (seg[mid] < b + 1) lo = mid + 1; else hi = mid; }
  const int end = lo;

  const int tid = threadIdx.x;  // 0..127
  const float4* __restrict__ emb4 = (const float4*)emb;
  float4 acc = make_float4(0.f, 0.f, 0.f, 0.f);

  int i = start;
  for (; i + 4 <= end; i += 4) {
    int t0 = tokens[i], t1 = tokens[i + 1], t2 = tokens[i + 2], t3 = tokens[i + 3];
    float4 v0 = emb4[(size_t)t0 * 128 + tid];
    float4 v1 = emb4[(size_t)t1 * 128 + tid];
    float4 v2 = emb4[(size_t)t2 * 128 + tid];
    float4 v3 = emb4[(size_t)t3 * 128 + tid];
    acc.x += v0.x + v1.x + v2.x + v3.x;
    acc.y += v0.y + v1.y + v2.y + v3.y;
    acc.z += v0.z + v1.z + v2.z + v3.z;
    acc.w += v0.w + v1.w + v2.w + v3.w;
  }
  for (; i < end; ++i) {
    int t0 = tokens[i];
    float4 v0 = emb4[(size_t)t0 * 128 + tid];
    acc.x += v0.x; acc.y += v0.y; acc.z += v0.z; acc.w += v0.w;
  }
  const int cnt = end - start;
  const float s = 1.0f / (float)(cnt > 0 ? cnt : 1);
  acc.x *= s; acc.y *= s; acc.z *= s; acc.w *= s;
  ((float4*)bow)[(size_t)b * 128 + tid] = acc;
}

// ---------------------------------------------------------------------------
// K2: z = bow @ W1^T + b1   (C[m][n] = sum_k A[m][k] * W[n][k] + b1[n])
// 64x64 tile, BK=32, 256 threads as 16x16, 4x4 micro-tile.
// LDS stored transposed ([k][m]) with +4 pad so fragment reads are float4.
// ---------------------------------------------------------------------------
constexpr int BM = 64, BN = 64, BK = 32;
constexpr int LST = BM + 4;  // 68: keeps float4 alignment, breaks pow2 stride

__global__ __launch_bounds__(256) void k_gemm(
    const float* __restrict__ A, const float* __restrict__ W,
    const float* __restrict__ b1, float* __restrict__ C) {
  __shared__ float As[BK][LST];
  __shared__ float Bs[BK][LST];
  const int tid = threadIdx.x;
  const int tx = tid & 15, ty = tid >> 4;
  const int bm0 = blockIdx.x * BM;
  const int bn0 = blockIdx.y * BN;

  const int lrow = tid >> 3;        // 0..31
  const int lc4  = (tid & 7) * 4;   // 0,4,...,28

  float acc[4][4] = {};

  for (int kc = 0; kc < H; kc += BK) {
    float4 a0 = *(const float4*)&A[(size_t)(bm0 + lrow)      * H + kc + lc4];
    float4 a1 = *(const float4*)&A[(size_t)(bm0 + lrow + 32) * H + kc + lc4];
    float4 w0 = *(const float4*)&W[(size_t)(bn0 + lrow)      * H + kc + lc4];
    float4 w1 = *(const float4*)&W[(size_t)(bn0 + lrow + 32) * H + kc + lc4];
    __syncthreads();  // previous iteration's compute done before overwrite
    As[lc4 + 0][lrow] = a0.x; As[lc4 + 1][lrow] = a0.y;
    As[lc4 + 2][lrow] = a0.z; As[lc4 + 3][lrow] = a0.w;
    As[lc4 + 0][lrow + 32] = a1.x; As[lc4 + 1][lrow + 32] = a1.y;
    As[lc4 + 2][lrow + 32] = a1.z; As[lc4 + 3][lrow + 32] = a1.w;
    Bs[lc4 + 0][lrow] = w0.x; Bs[lc4 + 1][lrow] = w0.y;
    Bs[lc4 + 2][lrow] = w0.z; Bs[lc4 + 3][lrow] = w0.w;
    Bs[lc4 + 0][lrow + 32] = w1.x; Bs[lc4 + 1][lrow + 32] = w1.y;
    Bs[lc4 + 2][lrow + 32] = w1.z; Bs[lc4 + 3][lrow + 32] = w1.w;
    __syncthreads();
#pragma unroll
    for (int k = 0; k < BK; ++k) {
      float4 av = *(const float4*)&As[k][ty * 4];
      float4 bv = *(const float4*)&Bs[k][tx * 4];
      acc[0][0] += av.x * bv.x; acc[0][1] += av.x * bv.y; acc[0][2] += av.x * bv.z; acc[0][3] += av.x * bv.w;
      acc[1][0] += av.y * bv.x; acc[1][1] += av.y * bv.y; acc[1][2] += av.y * bv.z; acc[1][3] += av.y * bv.w;
      acc[2][0] += av.z * bv.x; acc[2][1] += av.z * bv.y; acc[2][2] += av.z * bv.z; acc[2][3] += av.z * bv.w;
      acc[3][0] += av.w * bv.x; acc[3][1] += av.w * bv.y; acc[3][2] += av.w * bv.z; acc[3][3] += av.w * bv.w;
    }
  }
  const float4 bb = *(const float4*)&b1[bn0 + tx * 4];
#pragma unroll
  for (int i = 0; i < 4; ++i) {
    float4 o;
    o.x = acc[i][0] + bb.x; o.y = acc[i][1] + bb.y;
    o.z = acc[i][2] + bb.z; o.w = acc[i][3] + bb.w;
    *(float4*)&C[(size_t)(bm0 + ty * 4 + i) * H + bn0 + tx * 4] = o;
  }
}

// ---------------------------------------------------------------------------
// K3a: per-64-row-block partial column sums / sumsq of z.
// ---------------------------------------------------------------------------
__global__ __launch_bounds__(256) void k_colstats(
    const float* __restrict__ z, float* __restrict__ ps, float* __restrict__ pss) {
  const int blk = blockIdx.x;        // 0..63
  const int c0 = threadIdx.x * 2;    // two adjacent columns
  const int r0 = blk * 64;
  float s0 = 0, s1 = 0, q0 = 0, q1 = 0;
  for (int r = 0; r < 64; ++r) {
    float2 v = *(const float2*)&z[(size_t)(r0 + r) * H + c0];
    s0 += v.x; s1 += v.y;
    q0 += v.x * v.x; q1 += v.y * v.y;
  }
  ps[blk * H + c0] = s0; ps[blk * H + c0 + 1] = s1;
  pss[blk * H + c0] = q0; pss[blk * H + c0 + 1] = q1;
}

// ---------------------------------------------------------------------------
// K3b: finalize mu/var -> fused scale/shift (gamma, beta folded in).
// ---------------------------------------------------------------------------
__global__ __launch_bounds__(512) void k_finalize(
    const float* __restrict__ ps, const float* __restrict__ pss,
    const float* __restrict__ gamma, const float* __restrict__ beta,
    float* __restrict__ scale, float* __restrict__ shift) {
  const int c = threadIdx.x;  // 512 threads
  float s = 0, q = 0;
  for (int i = 0; i < 64; ++i) { s += ps[i * H + c]; q += pss[i * H + c]; }
  const float mu = s * (1.0f / NB);
  const float var = q * (1.0f / NB) - mu * mu;
  const float rstd = rsqrtf(var + EPS);
  const float sc = rstd * gamma[c];
  scale[c] = sc;
  shift[c] = beta[c] - mu * sc;
}

// ---------------------------------------------------------------------------
// K4: BN + ReLU + dot(w2) per row -> logits.  One wave per row.
// ---------------------------------------------------------------------------
__global__ __launch_bounds__(256) void k_bn_dot(
    const float* __restrict__ z, const float* __restrict__ scale,
    const float* __restrict__ shift, const float* __restrict__ w2,
    const float* __restrict__ b2, float* __restrict__ out) {
  const int tid = threadIdx.x;
  const int wave = tid >> 6, lane = tid & 63;
  const int b = blockIdx.x * 4 + wave;
  const float4* __restrict__ z4 = (const float4*)(z + (size_t)b * H);
  const float4* __restrict__ sc4 = (const float4*)scale;
  const float4* __restrict__ sh4 = (const float4*)shift;
  const float4* __restrict__ w24 = (const float4*)w2;
  float acc = 0.f;
#pragma unroll
  for (int i = lane; i < 128; i += 64) {
    float4 zv = z4[i], sc = sc4[i], sh = sh4[i], w = w24[i];
    float h0 = fmaxf(zv.x * sc.x + sh.x, 0.f);
    float h1 = fmaxf(zv.y * sc.y + sh.y, 0.f);
    float h2 = fmaxf(zv.z * sc.z + sh.z, 0.f);
    float h3 = fmaxf(zv.w * sc.w + sh.w, 0.f);
    acc += h0 * w.x + h1 * w.y + h2 * w.z + h3 * w.w;
  }
#pragma unroll
  for (int off = 32; off > 0; off >>= 1) acc += __shfl_down(acc, off, 64);
  if (lane == 0) out[1 + b] = acc + b2[0];
}

// ---------------------------------------------------------------------------
// K5: BCE-with-logits mean loss from logits in d_out[1..NB].
// ---------------------------------------------------------------------------
__global__ __launch_bounds__(256) void k_loss(
    const float* __restrict__ t, float* __restrict__ d_out) {
  const int tid = threadIdx.x;
  float s = 0.f;
  for (int b = tid; b < NB; b += 256) {
    float x = d_out[1 + b];
    float sp = fmaxf(x, 0.f) + log1pf(expf(-fabsf(x)));
    s += sp - t[b] * x;
  }
  __shared__ float red[256];
  red[tid] = s;
  __syncthreads();
  for (int off = 128; off > 0; off >>= 1) {
    if (tid < off) red[tid] += red[tid + off];
    __syncthreads();
  }
  if (tid == 0) d_out[0] = red[0] * (1.0f / NB);
}

// ---------------------------------------------------------------------------
extern "C" void kernel_launch(void* const* d_in, const int* in_sizes, int n_in,
                              void* d_out, int out_size, void* d_ws, size_t ws_size,
                              hipStream_t stream) {
  const int*   tokens = (const int*)d_in[0];
  const int*   seg    = (const int*)d_in[1];
  const float* t      = (const float*)d_in[2];
  const float* emb    = (const float*)d_in[3];
  const float* W1     = (const float*)d_in[4];
  const float* b1     = (const float*)d_in[5];
  const float* gamma  = (const float*)d_in[6];
  const float* beta   = (const float*)d_in[7];
  const float* w2     = (const float*)d_in[8];
  const float* b2     = (const float*)d_in[9];
  float* out = (float*)d_out;

  // workspace layout (floats)
  float* ws = (float*)d_ws;
  float* bow   = ws;                       // NB*H   = 2,097,152
  float* z     = bow + (size_t)NB * H;     // NB*H
  float* ps    = z + (size_t)NB * H;       // 64*H
  float* pss   = ps + 64 * H;              // 64*H
  float* scale = pss + 64 * H;             // H
  float* shift = scale + H;                // H

  k_gather_mean<<<NB, 128, 0, stream>>>(tokens, seg, emb, bow);
  dim3 ggrid(NB / BM, H / BN);
  k_gemm<<<ggrid, 256, 0, stream>>>(bow, W1, b1, z);
  k_colstats<<<64, 256, 0, stream>>>(z, ps, pss);
  k_finalize<<<1, 512, 0, stream>>>(ps, pss, gamma, beta, scale, shift);
  k_bn_dot<<<NB / 4, 256, 0, stream>>>(z, scale, shift, w2, b2, out);
  k_loss<<<1, 256, 0, stream>>>(t, out);
}

// Round 2
// 445.905 us; speedup vs baseline: 1.0348x; 1.0348x over previous
//
#include <hip/hip_runtime.h>
#include <hip/hip_bf16.h>
#include <hip/hip_fp16.h>
#include <math.h>

// Problem constants (from reference)
constexpr int NTOK = 524288;   // T
constexpr int NB   = 4096;     // B (segments / batch)
constexpr int H    = 512;
constexpr float EPS = 1e-5f;

struct h4 { __half2 a, b; };   // 8 bytes = 4 halves

// ---------------------------------------------------------------------------
// K0: convert emb fp32 -> fp16 (halves gather bytes; 102.4 MB fits L3).
// One float4 per thread; V*H/4 = 12.8M threads.
// ---------------------------------------------------------------------------
__global__ __launch_bounds__(256) void k_convert(
    const float* __restrict__ emb, h4* __restrict__ embh) {
  size_t i = (size_t)blockIdx.x * 256 + threadIdx.x;
  float4 v = ((const float4*)emb)[i];
  h4 o;
  o.a = __floats2half2_rn(v.x, v.y);
  o.b = __floats2half2_rn(v.z, v.w);
  embh[i] = o;
}

// ---------------------------------------------------------------------------
// K1: fused gather + segment mean (fp16 table, fp32 accum).
// seg_ids sorted -> one block per segment. 256 threads = 2 token-groups x
// 128 col-lanes (8 B/lane = 4 cols). LDS combine across groups.
// ---------------------------------------------------------------------------
__global__ __launch_bounds__(256) void k_gather_mean(
    const int* __restrict__ tokens, const int* __restrict__ seg,
    const h4* __restrict__ embh, float* __restrict__ bow) {
  const int b = blockIdx.x;
  int lo = 0, hi = NTOK;
  while (lo < hi) { int mid = (lo + hi) >> 1; if (seg[mid] < b) lo = mid + 1; else hi = mid; }
  const int start = lo;
  hi = NTOK;
  while (lo < hi) { int mid = (lo + hi) >> 1; if (seg[mid] < b + 1) lo = mid + 1; else hi = mid; }
  const int end = lo;

  const int tid = threadIdx.x;
  const int col = tid & 127;
  const int g = tid >> 7;      // token-parity group 0/1

  float4 acc = make_float4(0.f, 0.f, 0.f, 0.f);
  int i = start + g;
  // 4 tokens per step (parity-interleaved), 4 gathers in flight
  for (; i + 6 < end; i += 8) {
    int t0 = tokens[i], t1 = tokens[i + 2], t2 = tokens[i + 4], t3 = tokens[i + 6];
    h4 v0 = embh[(size_t)t0 * 128 + col];
    h4 v1 = embh[(size_t)t1 * 128 + col];
    h4 v2 = embh[(size_t)t2 * 128 + col];
    h4 v3 = embh[(size_t)t3 * 128 + col];
    float2 a0 = __half22float2(v0.a), b0 = __half22float2(v0.b);
    float2 a1 = __half22float2(v1.a), b1 = __half22float2(v1.b);
    float2 a2 = __half22float2(v2.a), b2 = __half22float2(v2.b);
    float2 a3 = __half22float2(v3.a), b3 = __half22float2(v3.b);
    acc.x += a0.x + a1.x + a2.x + a3.x;
    acc.y += a0.y + a1.y + a2.y + a3.y;
    acc.z += b0.x + b1.x + b2.x + b3.x;
    acc.w += b0.y + b1.y + b2.y + b3.y;
  }
  for (; i < end; i += 2) {
    h4 v0 = embh[(size_t)tokens[i] * 128 + col];
    float2 a0 = __half22float2(v0.a), b0 = __half22float2(v0.b);
    acc.x += a0.x; acc.y += a0.y; acc.z += b0.x; acc.w += b0.y;
  }

  __shared__ float4 part[128];
  if (g == 1) part[col] = acc;
  __syncthreads();
  if (g == 0) {
    float4 p = part[col];
    const int cnt = end - start;
    const float s = 1.0f / (float)(cnt > 0 ? cnt : 1);
    acc.x = (acc.x + p.x) * s; acc.y = (acc.y + p.y) * s;
    acc.z = (acc.z + p.z) * s; acc.w = (acc.w + p.w) * s;
    ((float4*)bow)[(size_t)b * 128 + col] = acc;
  }
}

// ---------------------------------------------------------------------------
// K2: z = bow @ W1^T + b1   (C[m][n] = sum_k A[m][k] * W[n][k] + b1[n])
// 64x64 tile, BK=32, 256 threads as 16x16, 4x4 micro-tile.
// ---------------------------------------------------------------------------
constexpr int BM = 64, BN = 64, BK = 32;
constexpr int LST = BM + 4;

__global__ __launch_bounds__(256) void k_gemm(
    const float* __restrict__ A, const float* __restrict__ W,
    const float* __restrict__ b1, float* __restrict__ C) {
  __shared__ float As[BK][LST];
  __shared__ float Bs[BK][LST];
  const int tid = threadIdx.x;
  const int tx = tid & 15, ty = tid >> 4;
  const int bm0 = blockIdx.x * BM;
  const int bn0 = blockIdx.y * BN;

  const int lrow = tid >> 3;
  const int lc4  = (tid & 7) * 4;

  float acc[4][4] = {};

  for (int kc = 0; kc < H; kc += BK) {
    float4 a0 = *(const float4*)&A[(size_t)(bm0 + lrow)      * H + kc + lc4];
    float4 a1 = *(const float4*)&A[(size_t)(bm0 + lrow + 32) * H + kc + lc4];
    float4 w0 = *(const float4*)&W[(size_t)(bn0 + lrow)      * H + kc + lc4];
    float4 w1 = *(const float4*)&W[(size_t)(bn0 + lrow + 32) * H + kc + lc4];
    __syncthreads();
    As[lc4 + 0][lrow] = a0.x; As[lc4 + 1][lrow] = a0.y;
    As[lc4 + 2][lrow] = a0.z; As[lc4 + 3][lrow] = a0.w;
    As[lc4 + 0][lrow + 32] = a1.x; As[lc4 + 1][lrow + 32] = a1.y;
    As[lc4 + 2][lrow + 32] = a1.z; As[lc4 + 3][lrow + 32] = a1.w;
    Bs[lc4 + 0][lrow] = w0.x; Bs[lc4 + 1][lrow] = w0.y;
    Bs[lc4 + 2][lrow] = w0.z; Bs[lc4 + 3][lrow] = w0.w;
    Bs[lc4 + 0][lrow + 32] = w1.x; Bs[lc4 + 1][lrow + 32] = w1.y;
    Bs[lc4 + 2][lrow + 32] = w1.z; Bs[lc4 + 3][lrow + 32] = w1.w;
    __syncthreads();
#pragma unroll
    for (int k = 0; k < BK; ++k) {
      float4 av = *(const float4*)&As[k][ty * 4];
      float4 bv = *(const float4*)&Bs[k][tx * 4];
      acc[0][0] += av.x * bv.x; acc[0][1] += av.x * bv.y; acc[0][2] += av.x * bv.z; acc[0][3] += av.x * bv.w;
      acc[1][0] += av.y * bv.x; acc[1][1] += av.y * bv.y; acc[1][2] += av.y * bv.z; acc[1][3] += av.y * bv.w;
      acc[2][0] += av.z * bv.x; acc[2][1] += av.z * bv.y; acc[2][2] += av.z * bv.z; acc[2][3] += av.z * bv.w;
      acc[3][0] += av.w * bv.x; acc[3][1] += av.w * bv.y; acc[3][2] += av.w * bv.z; acc[3][3] += av.w * bv.w;
    }
  }
  const float4 bb = *(const float4*)&b1[bn0 + tx * 4];
#pragma unroll
  for (int i = 0; i < 4; ++i) {
    float4 o;
    o.x = acc[i][0] + bb.x; o.y = acc[i][1] + bb.y;
    o.z = acc[i][2] + bb.z; o.w = acc[i][3] + bb.w;
    *(float4*)&C[(size_t)(bm0 + ty * 4 + i) * H + bn0 + tx * 4] = o;
  }
}

// ---------------------------------------------------------------------------
// K3a: per-64-row-block partial column sums / sumsq of z.
// ---------------------------------------------------------------------------
__global__ __launch_bounds__(256) void k_colstats(
    const float* __restrict__ z, float* __restrict__ ps, float* __restrict__ pss) {
  const int blk = blockIdx.x;
  const int c0 = threadIdx.x * 2;
  const int r0 = blk * 64;
  float s0 = 0, s1 = 0, q0 = 0, q1 = 0;
  for (int r = 0; r < 64; ++r) {
    float2 v = *(const float2*)&z[(size_t)(r0 + r) * H + c0];
    s0 += v.x; s1 += v.y;
    q0 += v.x * v.x; q1 += v.y * v.y;
  }
  ps[blk * H + c0] = s0; ps[blk * H + c0 + 1] = s1;
  pss[blk * H + c0] = q0; pss[blk * H + c0 + 1] = q1;
}

// ---------------------------------------------------------------------------
// K3b: finalize mu/var -> fused scale/shift (gamma, beta folded in).
// ---------------------------------------------------------------------------
__global__ __launch_bounds__(512) void k_finalize(
    const float* __restrict__ ps, const float* __restrict__ pss,
    const float* __restrict__ gamma, const float* __restrict__ beta,
    float* __restrict__ scale, float* __restrict__ shift) {
  const int c = threadIdx.x;
  float s = 0, q = 0;
  for (int i = 0; i < 64; ++i) { s += ps[i * H + c]; q += pss[i * H + c]; }
  const float mu = s * (1.0f / NB);
  const float var = q * (1.0f / NB) - mu * mu;
  const float rstd = rsqrtf(var + EPS);
  const float sc = rstd * gamma[c];
  scale[c] = sc;
  shift[c] = beta[c] - mu * sc;
}

// ---------------------------------------------------------------------------
// K4: BN + ReLU + dot(w2) per row -> logits.  One wave per row.
// ---------------------------------------------------------------------------
__global__ __launch_bounds__(256) void k_bn_dot(
    const float* __restrict__ z, const float* __restrict__ scale,
    const float* __restrict__ shift, const float* __restrict__ w2,
    const float* __restrict__ b2, float* __restrict__ out) {
  const int tid = threadIdx.x;
  const int wave = tid >> 6, lane = tid & 63;
  const int b = blockIdx.x * 4 + wave;
  const float4* __restrict__ z4 = (const float4*)(z + (size_t)b * H);
  const float4* __restrict__ sc4 = (const float4*)scale;
  const float4* __restrict__ sh4 = (const float4*)shift;
  const float4* __restrict__ w24 = (const float4*)w2;
  float acc = 0.f;
#pragma unroll
  for (int i = lane; i < 128; i += 64) {
    float4 zv = z4[i], sc = sc4[i], sh = sh4[i], w = w24[i];
    float h0 = fmaxf(zv.x * sc.x + sh.x, 0.f);
    float h1 = fmaxf(zv.y * sc.y + sh.y, 0.f);
    float h2 = fmaxf(zv.z * sc.z + sh.z, 0.f);
    float h3 = fmaxf(zv.w * sc.w + sh.w, 0.f);
    acc += h0 * w.x + h1 * w.y + h2 * w.z + h3 * w.w;
  }
#pragma unroll
  for (int off = 32; off > 0; off >>= 1) acc += __shfl_down(acc, off, 64);
  if (lane == 0) out[1 + b] = acc + b2[0];
}

// ---------------------------------------------------------------------------
// K5: BCE-with-logits mean loss from logits in d_out[1..NB].
// ---------------------------------------------------------------------------
__global__ __launch_bounds__(256) void k_loss(
    const float* __restrict__ t, float* __restrict__ d_out) {
  const int tid = threadIdx.x;
  float s = 0.f;
  for (int b = tid; b < NB; b += 256) {
    float x = d_out[1 + b];
    float sp = fmaxf(x, 0.f) + log1pf(expf(-fabsf(x)));
    s += sp - t[b] * x;
  }
  __shared__ float red[256];
  red[tid] = s;
  __syncthreads();
  for (int off = 128; off > 0; off >>= 1) {
    if (tid < off) red[tid] += red[tid + off];
    __syncthreads();
  }
  if (tid == 0) d_out[0] = red[0] * (1.0f / NB);
}

// ---------------------------------------------------------------------------
extern "C" void kernel_launch(void* const* d_in, const int* in_sizes, int n_in,
                              void* d_out, int out_size, void* d_ws, size_t ws_size,
                              hipStream_t stream) {
  const int*   tokens = (const int*)d_in[0];
  const int*   seg    = (const int*)d_in[1];
  const float* t      = (const float*)d_in[2];
  const float* emb    = (const float*)d_in[3];
  const float* W1     = (const float*)d_in[4];
  const float* b1     = (const float*)d_in[5];
  const float* gamma  = (const float*)d_in[6];
  const float* beta   = (const float*)d_in[7];
  const float* w2     = (const float*)d_in[8];
  const float* b2     = (const float*)d_in[9];
  float* out = (float*)d_out;

  // workspace layout
  char* wsb = (char*)d_ws;
  h4*    embh  = (h4*)wsb;                               // 102,400,000 B
  float* bow   = (float*)(wsb + 102400000);              // NB*H floats = 8 MB
  float* z     = bow + (size_t)NB * H;                   // 8 MB
  float* ps    = z + (size_t)NB * H;                     // 64*H
  float* pss   = ps + 64 * H;
  float* scale = pss + 64 * H;
  float* shift = scale + H;

  // V*H/4 float4s = 12,800,000 -> 50,000 blocks x 256
  k_convert<<<50000, 256, 0, stream>>>(emb, embh);
  k_gather_mean<<<NB, 256, 0, stream>>>(tokens, seg, embh, bow);
  dim3 ggrid(NB / BM, H / BN);
  k_gemm<<<ggrid, 256, 0, stream>>>(bow, W1, b1, z);
  k_colstats<<<64, 256, 0, stream>>>(z, ps, pss);
  k_finalize<<<1, 512, 0, stream>>>(ps, pss, gamma, beta, scale, shift);
  k_bn_dot<<<NB / 4, 256, 0, stream>>>(z, scale, shift, w2, b2, out);
  k_loss<<<1, 256, 0, stream>>>(t, out);
}

// Round 3
// 420.266 us; speedup vs baseline: 1.0980x; 1.0610x over previous
//
#include <hip/hip_runtime.h>
#include <hip/hip_bf16.h>
#include <hip/hip_fp16.h>
#include <math.h>

constexpr int NTOK = 524288;   // T
constexpr int NB   = 4096;     // B
constexpr int H    = 512;
constexpr float EPS = 1e-5f;

typedef _Float16 half8 __attribute__((ext_vector_type(8)));
typedef float f32x4 __attribute__((ext_vector_type(4)));
struct h4 { __half2 a, b; };   // 8 bytes = 4 halves

// ---------------------------------------------------------------------------
// K0: fp32 -> fp16 convert (used for emb [big] and W1 [tiny]).
// Grid must exactly cover count/4 float4s.
// ---------------------------------------------------------------------------
__global__ __launch_bounds__(256) void k_convert(
    const float* __restrict__ src, h4* __restrict__ dst) {
  size_t i = (size_t)blockIdx.x * 256 + threadIdx.x;
  float4 v = ((const float4*)src)[i];
  h4 o;
  o.a = __floats2half2_rn(v.x, v.y);
  o.b = __floats2half2_rn(v.z, v.w);
  dst[i] = o;
}

// ---------------------------------------------------------------------------
// K1: fused gather + segment mean (fp16 table, fp32 accum, fp16 bow out).
// 256 threads = 4 token-groups x 64 lanes; each lane owns 16 B (8 cols).
// 4-deep unroll -> 16 rows in flight per block.
// ---------------------------------------------------------------------------
__global__ __launch_bounds__(256) void k_gather_mean(
    const int* __restrict__ tokens, const int* __restrict__ seg,
    const half8* __restrict__ embh, half8* __restrict__ bow_h) {
  const int b = blockIdx.x;
  int lo = 0, hi = NTOK;
  while (lo < hi) { int mid = (lo + hi) >> 1; if (seg[mid] < b) lo = mid + 1; else hi = mid; }
  const int start = lo;
  hi = NTOK;
  while (lo < hi) { int mid = (lo + hi) >> 1; if (seg[mid] < b + 1) lo = mid + 1; else hi = mid; }
  const int end = lo;

  const int tid = threadIdx.x;
  const int lane = tid & 63;
  const int g = tid >> 6;

  float acc[8] = {};
  int i = start + g;
  for (; i + 12 < end; i += 16) {
    half8 v0 = embh[(size_t)tokens[i]      * 64 + lane];
    half8 v1 = embh[(size_t)tokens[i + 4]  * 64 + lane];
    half8 v2 = embh[(size_t)tokens[i + 8]  * 64 + lane];
    half8 v3 = embh[(size_t)tokens[i + 12] * 64 + lane];
#pragma unroll
    for (int j = 0; j < 8; ++j)
      acc[j] += (float)v0[j] + (float)v1[j] + (float)v2[j] + (float)v3[j];
  }
  for (; i < end; i += 4) {
    half8 v0 = embh[(size_t)tokens[i] * 64 + lane];
#pragma unroll
    for (int j = 0; j < 8; ++j) acc[j] += (float)v0[j];
  }

  __shared__ float part[3][64][9];   // +1 pad breaks bank aliasing
  if (g > 0) {
#pragma unroll
    for (int j = 0; j < 8; ++j) part[g - 1][lane][j] = acc[j];
  }
  __syncthreads();
  if (g == 0) {
    const int cnt = end - start;
    const float s = 1.0f / (float)(cnt > 0 ? cnt : 1);
    half8 o;
#pragma unroll
    for (int j = 0; j < 8; ++j) {
      float v = acc[j] + part[0][lane][j] + part[1][lane][j] + part[2][lane][j];
      o[j] = (_Float16)(v * s);
    }
    bow_h[(size_t)b * 64 + lane] = o;
  }
}

// ---------------------------------------------------------------------------
// K2: z = bow @ W1^T + b1 via fp16 MFMA, fp32 accum.
// Per wave: 16 m-rows x 64 n-cols (4 frags), K=512 fully in-register loop.
// No LDS: A/B frag loads are 16 B/lane straight from L2.
// Layouts (verified, learn_hip m89/m120): A[m=lane&15][k=quad*8+j],
// B[k=quad*8+j][n=lane&15], D: col=lane&15, row=quad*4+reg.
// B[k][n] = W1[n][k] -> both frags read 8 contiguous k from a row. 
// ---------------------------------------------------------------------------
__global__ __launch_bounds__(256) void k_gemm_mfma(
    const _Float16* __restrict__ A,   // bow_h [NB][H]
    const _Float16* __restrict__ Bw,  // W1h   [H][H]
    const float* __restrict__ b1, float* __restrict__ C) {
  const int tid = threadIdx.x;
  const int lane = tid & 63;
  const int gw = blockIdx.x * 4 + (tid >> 6);   // 2048 waves total
  const int m0 = (gw >> 3) * 16;                // 256 m-tiles
  const int n0 = (gw & 7) * 64;                 // 8 n-groups
  const int l15 = lane & 15, quad = lane >> 4;

  f32x4 acc0 = {}, acc1 = {}, acc2 = {}, acc3 = {};
  const _Float16* ap = A + (size_t)(m0 + l15) * H + quad * 8;
  const _Float16* bp = Bw + (size_t)(n0 + l15) * H + quad * 8;

#pragma unroll
  for (int k = 0; k < H; k += 32) {
    half8 af  = *(const half8*)(ap + k);
    half8 bf0 = *(const half8*)(bp + k);
    half8 bf1 = *(const half8*)(bp + 16 * H + k);
    half8 bf2 = *(const half8*)(bp + 32 * H + k);
    half8 bf3 = *(const half8*)(bp + 48 * H + k);
    acc0 = __builtin_amdgcn_mfma_f32_16x16x32_f16(af, bf0, acc0, 0, 0, 0);
    acc1 = __builtin_amdgcn_mfma_f32_16x16x32_f16(af, bf1, acc1, 0, 0, 0);
    acc2 = __builtin_amdgcn_mfma_f32_16x16x32_f16(af, bf2, acc2, 0, 0, 0);
    acc3 = __builtin_amdgcn_mfma_f32_16x16x32_f16(af, bf3, acc3, 0, 0, 0);
  }

  const float bn0v = b1[n0 + l15];
  const float bn1v = b1[n0 + 16 + l15];
  const float bn2v = b1[n0 + 32 + l15];
  const float bn3v = b1[n0 + 48 + l15];
  float* crow = C + (size_t)(m0 + quad * 4) * H + n0 + l15;
#pragma unroll
  for (int r = 0; r < 4; ++r) {
    crow[(size_t)r * H]      = acc0[r] + bn0v;
    crow[(size_t)r * H + 16] = acc1[r] + bn1v;
    crow[(size_t)r * H + 32] = acc2[r] + bn2v;
    crow[(size_t)r * H + 48] = acc3[r] + bn3v;
  }
}

// ---------------------------------------------------------------------------
// K3a: per-64-row-block partial column sums / sumsq of z.
// ---------------------------------------------------------------------------
__global__ __launch_bounds__(256) void k_colstats(
    const float* __restrict__ z, float* __restrict__ ps, float* __restrict__ pss) {
  const int blk = blockIdx.x;
  const int c0 = threadIdx.x * 2;
  const int r0 = blk * 64;
  float s0 = 0, s1 = 0, q0 = 0, q1 = 0;
  for (int r = 0; r < 64; ++r) {
    float2 v = *(const float2*)&z[(size_t)(r0 + r) * H + c0];
    s0 += v.x; s1 += v.y;
    q0 += v.x * v.x; q1 += v.y * v.y;
  }
  ps[blk * H + c0] = s0; ps[blk * H + c0 + 1] = s1;
  pss[blk * H + c0] = q0; pss[blk * H + c0 + 1] = q1;
}

// ---------------------------------------------------------------------------
// K3b: finalize mu/var -> fused scale/shift.  4 blocks x 128 threads.
// ---------------------------------------------------------------------------
__global__ __launch_bounds__(128) void k_finalize(
    const float* __restrict__ ps, const float* __restrict__ pss,
    const float* __restrict__ gamma, const float* __restrict__ beta,
    float* __restrict__ scale, float* __restrict__ shift) {
  const int c = blockIdx.x * 128 + threadIdx.x;
  float s = 0, q = 0;
#pragma unroll 8
  for (int i = 0; i < 64; ++i) { s += ps[i * H + c]; q += pss[i * H + c]; }
  const float mu = s * (1.0f / NB);
  const float var = q * (1.0f / NB) - mu * mu;
  const float rstd = rsqrtf(var + EPS);
  const float sc = rstd * gamma[c];
  scale[c] = sc;
  shift[c] = beta[c] - mu * sc;
}

// ---------------------------------------------------------------------------
// K4: BN + ReLU + dot(w2) per row -> logits.  One wave per row.
// ---------------------------------------------------------------------------
__global__ __launch_bounds__(256) void k_bn_dot(
    const float* __restrict__ z, const float* __restrict__ scale,
    const float* __restrict__ shift, const float* __restrict__ w2,
    const float* __restrict__ b2, float* __restrict__ out) {
  const int tid = threadIdx.x;
  const int wave = tid >> 6, lane = tid & 63;
  const int b = blockIdx.x * 4 + wave;
  const float4* __restrict__ z4 = (const float4*)(z + (size_t)b * H);
  const float4* __restrict__ sc4 = (const float4*)scale;
  const float4* __restrict__ sh4 = (const float4*)shift;
  const float4* __restrict__ w24 = (const float4*)w2;
  float acc = 0.f;
#pragma unroll
  for (int i = lane; i < 128; i += 64) {
    float4 zv = z4[i], sc = sc4[i], sh = sh4[i], w = w24[i];
    float h0 = fmaxf(zv.x * sc.x + sh.x, 0.f);
    float h1 = fmaxf(zv.y * sc.y + sh.y, 0.f);
    float h2 = fmaxf(zv.z * sc.z + sh.z, 0.f);
    float h3 = fmaxf(zv.w * sc.w + sh.w, 0.f);
    acc += h0 * w.x + h1 * w.y + h2 * w.z + h3 * w.w;
  }
#pragma unroll
  for (int off = 32; off > 0; off >>= 1) acc += __shfl_down(acc, off, 64);
  if (lane == 0) out[1 + b] = acc + b2[0];
}

// ---------------------------------------------------------------------------
// K5: BCE-with-logits mean loss.  1024 threads, 4 logits each.
// ---------------------------------------------------------------------------
__global__ __launch_bounds__(1024) void k_loss(
    const float* __restrict__ t, float* __restrict__ d_out) {
  const int tid = threadIdx.x;
  float s = 0.f;
#pragma unroll
  for (int b = tid; b < NB; b += 1024) {
    float x = d_out[1 + b];
    float sp = fmaxf(x, 0.f) + log1pf(expf(-fabsf(x)));
    s += sp - t[b] * x;
  }
  __shared__ float red[1024];
  red[tid] = s;
  __syncthreads();
  for (int off = 512; off > 0; off >>= 1) {
    if (tid < off) red[tid] += red[tid + off];
    __syncthreads();
  }
  if (tid == 0) d_out[0] = red[0] * (1.0f / NB);
}

// ---------------------------------------------------------------------------
extern "C" void kernel_launch(void* const* d_in, const int* in_sizes, int n_in,
                              void* d_out, int out_size, void* d_ws, size_t ws_size,
                              hipStream_t stream) {
  const int*   tokens = (const int*)d_in[0];
  const int*   seg    = (const int*)d_in[1];
  const float* t      = (const float*)d_in[2];
  const float* emb    = (const float*)d_in[3];
  const float* W1     = (const float*)d_in[4];
  const float* b1     = (const float*)d_in[5];
  const float* gamma  = (const float*)d_in[6];
  const float* beta   = (const float*)d_in[7];
  const float* w2     = (const float*)d_in[8];
  const float* b2     = (const float*)d_in[9];
  float* out = (float*)d_out;

  // workspace layout (bytes)
  char* wsb = (char*)d_ws;
  half8*    embh  = (half8*)wsb;                          // 100000*512*2 = 102,400,000
  _Float16* W1h   = (_Float16*)(wsb + 102400000);         // 512*512*2 = 524,288
  half8*    bow_h = (half8*)(wsb + 102924288);            // 4096*512*2 = 4,194,304
  float*    z     = (float*)(wsb + 107118592);            // 4096*512*4 = 8,388,608
  float*    ps    = (float*)(wsb + 115507200);            // 64*512*4
  float*    pss   = ps + 64 * H;
  float*    scale = pss + 64 * H;
  float*    shift = scale + H;

  // emb: 100000*512/4 = 12,800,000 float4 -> 50000 blocks
  k_convert<<<50000, 256, 0, stream>>>(emb, (h4*)embh);
  // W1: 512*512/4 = 65536 float4 -> 256 blocks
  k_convert<<<256, 256, 0, stream>>>(W1, (h4*)W1h);
  k_gather_mean<<<NB, 256, 0, stream>>>(tokens, seg, embh, bow_h);
  k_gemm_mfma<<<512, 256, 0, stream>>>((const _Float16*)bow_h, W1h, b1, z);
  k_colstats<<<64, 256, 0, stream>>>(z, ps, pss);
  k_finalize<<<4, 128, 0, stream>>>(ps, pss, gamma, beta, scale, shift);
  k_bn_dot<<<NB / 4, 256, 0, stream>>>(z, scale, shift, w2, b2, out);
  k_loss<<<1, 1024, 0, stream>>>(t, out);
}